// Round 18
// baseline (1699.392 us; speedup 1.0000x reference)
//
#include <hip/hip_runtime.h>
#include <hip/hip_bf16.h>

#define B_    8
#define N_    4096
#define D_    64
#define NP_   1024
#define K_    32
#define NC_   212
#define CO_   128
#define FPS_T 256
#define SVW   72
#define PROWS 139

__device__ __forceinline__ float f32add(float a, float b) { return __fadd_rn(a, b); }
__device__ __forceinline__ float f32sub(float a, float b) { return __fsub_rn(a, b); }
__device__ __forceinline__ float f32mul(float a, float b) { return __fmul_rn(a, b); }

__device__ __forceinline__ void waveArgmaxDpp(float& best, int& bidx) {
#define AMAX_STEP(CTRL)                                                                     \
    {                                                                                       \
        int _v = __builtin_amdgcn_update_dpp(__float_as_int(best), __float_as_int(best),    \
                                             (CTRL), 0xf, 0xf, false);                      \
        int _i = __builtin_amdgcn_update_dpp(bidx, bidx, (CTRL), 0xf, 0xf, false);          \
        float _f = __int_as_float(_v);                                                      \
        if (_f > best || (_f == best && _i < bidx)) { best = _f; bidx = _i; }               \
    }
    AMAX_STEP(0x111); AMAX_STEP(0x112); AMAX_STEP(0x114);
    AMAX_STEP(0x118); AMAX_STEP(0x142); AMAX_STEP(0x143);
#undef AMAX_STEP
    best = __int_as_float(__builtin_amdgcn_readlane(__float_as_int(best), 63));
    bidx = __builtin_amdgcn_readlane(bidx, 63);
}

// ---------------------------------------------------------------------------
// Kernel A: fold A into P[139][212] (one-time, proven r16).
// ---------------------------------------------------------------------------
__global__ void fold_kernel(const float* __restrict__ A, float* __restrict__ P) {
    int x = blockIdx.x * 256 + threadIdx.x;
    if (x >= PROWS * NC_) return;
    int r = x / NC_, c = x % NC_;
    float v;
    if      (r < 64)  v = A[(size_t)(77 + r) * NC_ + c] + A[(size_t)(144 + r) * NC_ + c];
    else if (r < 67)  { int j = r - 64;
                        v = (A[(size_t)(3 + j) * NC_ + c] + A[(size_t)(141 + j) * NC_ + c])
                          + A[(size_t)(208 + j) * NC_ + c]; }
    else if (r < 70)  { int j = r - 67;
                        v = A[(size_t)(74 + j) * NC_ + c] - A[(size_t)(208 + j) * NC_ + c]; }
    else if (r < 73)  { int j = r - 70;
                        v = A[(size_t)j * NC_ + c] - A[(size_t)(6 + j) * NC_ + c]; }
    else if (r == 73) v = A[(size_t)9 * NC_ + c];
    else if (r < 138) { int i = r - 74;
                        v = A[(size_t)(10 + i) * NC_ + c] - A[(size_t)(144 + i) * NC_ + c]; }
    else              v = A[(size_t)211 * NC_ + c];
    P[(size_t)r * NC_ + c] = v;
}

// ---------------------------------------------------------------------------
// Kernel B: transpose features (B,64,N) -> featT (B,N,64) (proven r16).
// ---------------------------------------------------------------------------
__global__ void transpose_kernel(const float* __restrict__ in, float* __restrict__ out) {
    __shared__ float tile[32][33];
    int b  = blockIdx.z;
    int n0 = blockIdx.x * 32, d0 = blockIdx.y * 32;
    const float* src = in  + (size_t)b * D_ * N_;
    float*       dst = out + (size_t)b * N_ * D_;
    int tx = threadIdx.x, ty = threadIdx.y;
#pragma unroll
    for (int r = 0; r < 32; r += 8)
        tile[r + ty][tx] = src[(size_t)(d0 + r + ty) * N_ + n0 + tx];
    __syncthreads();
#pragma unroll
    for (int r = 0; r < 32; r += 8)
        dst[(size_t)(n0 + r + ty) * D_ + d0 + tx] = tile[tx][r + ty];
}

// ---------------------------------------------------------------------------
// Kernel 1: FPS — r8-proven structure (4 waves/batch, DPP argmax, parity
// merge) + tree-select over the 16 per-thread candidates (was a 16-deep
// SERIAL compare chain). Tree merge = (max value, min index) — associative,
// reproduces np.argmax first-max exactly. Distance math bit-exact vs numpy.
// ---------------------------------------------------------------------------
__global__ __launch_bounds__(FPS_T) void fps_kernel(
    const float* __restrict__ xyz,
    int* __restrict__ fpsIdx, float* __restrict__ out0) {
    int b = blockIdx.x;
    const float* P = xyz + (size_t)b * N_ * 3;
    __shared__ float X[N_], Y[N_], Z[N_];
    __shared__ int   hist[NP_];
    __shared__ float redV[2][FPS_T / 64];
    __shared__ int   redI[2][FPS_T / 64];
    int tid = threadIdx.x;
    for (int i = tid; i < N_; i += FPS_T) {
        X[i] = P[i * 3 + 0];
        Y[i] = P[i * 3 + 1];
        Z[i] = P[i * 3 + 2];
    }
    if (tid == 0) hist[0] = 0;
    __syncthreads();

    const int PPT = N_ / FPS_T;  // 16
    float px[PPT], py[PPT], pz[PPT], dist[PPT];
#pragma unroll
    for (int c = 0; c < PPT; c++) {
        int j = tid + FPS_T * c;
        px[c] = X[j]; py[c] = Y[j]; pz[c] = Z[j];
        dist[c] = 1e10f;
    }
    int last = 0;
    for (int it = 1; it < NP_; ++it) {
        float lx = X[last], ly = Y[last], lz = Z[last];
#pragma unroll
        for (int c = 0; c < PPT; c++) {
            float dx = f32sub(px[c], lx), dy = f32sub(py[c], ly), dz = f32sub(pz[c], lz);
            float nd = f32add(f32add(f32mul(dx, dx), f32mul(dy, dy)), f32mul(dz, dz));
            dist[c] = fminf(dist[c], nd);
        }
        // tree argmax over 16 candidates (max value, min index on tie)
        float tv[8]; int tc[8];
#pragma unroll
        for (int c = 0; c < 8; c++) {
            bool t = dist[c + 8] > dist[c];            // tie keeps lower index c
            tv[c] = t ? dist[c + 8] : dist[c];
            tc[c] = t ? c + 8 : c;
        }
#pragma unroll
        for (int s = 4; s >= 1; s >>= 1)
#pragma unroll
            for (int c = 0; c < s; c++) {
                bool t = (tv[c + s] > tv[c]) || (tv[c + s] == tv[c] && tc[c + s] < tc[c]);
                if (t) { tv[c] = tv[c + s]; tc[c] = tc[c + s]; }
            }
        float best = tv[0]; int bidx = tid + FPS_T * tc[0];
        waveArgmaxDpp(best, bidx);
        int par = it & 1;
        if ((tid & 63) == 0) { redV[par][tid >> 6] = best; redI[par][tid >> 6] = bidx; }
        __syncthreads();  // single barrier per iter; parity double-buffer makes it safe
        float bv = redV[par][0]; int bi = redI[par][0];
#pragma unroll
        for (int w = 1; w < FPS_T / 64; w++) {
            float ov = redV[par][w]; int oi = redI[par][w];
            if (ov > bv || (ov == bv && oi < bi)) { bv = ov; bi = oi; }
        }
        last = bi;
        if (tid == 0) hist[it] = last;
    }
    __syncthreads();
    for (int i = tid; i < NP_; i += FPS_T) {
        int j = hist[i];
        fpsIdx[b * NP_ + i] = j;
        size_t o = (size_t)(b * NP_ + i) * 3;
        out0[o + 0] = X[j]; out0[o + 1] = Y[j]; out0[o + 2] = Z[j];
    }
}

// ---------------------------------------------------------------------------
// Kernel 2: fused ball-query + feature_enhance + hetero_attention
// (EXACTLY the passing round-16 kernel: featT gathers + folded-P e-GEMM).
// ---------------------------------------------------------------------------
__global__ __launch_bounds__(256, 4) void fused_kernel(
    const float* __restrict__ featT, const float* __restrict__ xyz,
    const float* __restrict__ newxyz, const int* __restrict__ fpsIdx,
    const float* __restrict__ P, const float* __restrict__ W1,
    const float* __restrict__ B1, float* __restrict__ out1) {
    int q = blockIdx.x;
    int b = q >> 10, n = q & (NP_ - 1);
    int tid = threadIdx.x;
    __shared__ float sV[K_][SVW];
    __shared__ float sF[68];
    __shared__ float sFD[K_];
    __shared__ float sGD[3];
    __shared__ float sGsum[3];
    __shared__ float sPool[NC_];
    __shared__ int   sNb[K_];
    __shared__ int   sCnt;

    if (tid < D_) sF[tid] = featT[((size_t)b * N_ + fpsIdx[q]) * D_ + tid];
    if (tid >= D_ && tid < D_ + 3) sF[tid] = newxyz[q * 3 + (tid - D_)];

    if (tid < 64) {
        int lane = tid;
        if (lane < K_) sNb[lane] = N_ - 1;
        const float* Px = xyz + (size_t)b * N_ * 3;
        float qx = newxyz[q * 3 + 0];
        float qy = newxyz[q * 3 + 1];
        float qz = newxyz[q * 3 + 2];
        float sq = f32add(f32add(f32mul(qx, qx), f32mul(qy, qy)), f32mul(qz, qz));
        const float R2 = (float)(0.2 * 0.2);
        int count = 0;
        for (int base = 0; base < N_ && count < K_; base += 64) {
            int j = base + lane;
            float x = Px[j * 3 + 0];
            float y = Px[j * 3 + 1];
            float z = Px[j * 3 + 2];
            float sxj = f32add(f32add(f32mul(x, x), f32mul(y, y)), f32mul(z, z));
            float dot = __fmaf_rn(qz, z, __fmaf_rn(qy, y, __fmul_rn(qx, x)));
            float d2  = f32sub(f32add(sq, sxj), f32mul(2.0f, dot));
            bool in = (d2 <= R2);
            unsigned long long m = __ballot(in);
            if (in) {
                int pos = count + __popcll(m & ((1ull << lane) - 1ull));
                if (pos < K_) sNb[pos] = j;
            }
            count += __popcll(m);
        }
        if (lane == 0) sCnt = (count < K_) ? count : K_;
    }
    __syncthreads();
    int cnt = sCnt;

    {
        int k = tid >> 3, l = tid & 7;
        int j = (k < cnt || cnt == 0) ? sNb[k] : sNb[0];
        const float* src = featT + ((size_t)b * N_ + j) * D_;
        float4 v0 = *(const float4*)(src + l * 8);
        float4 v1 = *(const float4*)(src + l * 8 + 4);
        float* dst = &sV[k][4 + l * 8];
        dst[0] = v0.x; dst[1] = v0.y; dst[2] = v0.z; dst[3] = v0.w;
        dst[4] = v1.x; dst[5] = v1.y; dst[6] = v1.z; dst[7] = v1.w;
    }
    if (tid < 96) {
        int k = tid / 3, c = tid % 3;
        int j = (k < cnt || cnt == 0) ? sNb[k] : sNb[0];
        sV[k][c] = xyz[((size_t)b * N_ + j) * 3 + c];
        sV[k][69 + c] = 0.f;
    }
    __syncthreads();

    {
        int k = tid >> 3, ds = (tid & 7) * 8;
        float s = 0.f;
#pragma unroll
        for (int j = 0; j < 8; j++) s += fabsf(sF[ds + j] - sV[k][4 + ds + j]);
        s += __shfl_xor(s, 1); s += __shfl_xor(s, 2); s += __shfl_xor(s, 4);
        if ((tid & 7) == 0) sFD[k] = __expf(-s * (1.0f / 64.0f));
    }
    __syncthreads();

    if (tid < 96) {
        int k = tid / 3, c = tid % 3;
        sV[k][c] = sV[k][c] * sFD[k];
    }
    __syncthreads();

    if (tid < K_) {
        int k = tid;
        float a0 = sF[64] - sV[k][0], a1 = sF[65] - sV[k][1], a2 = sF[66] - sV[k][2];
        sV[k][3] = sqrtf(a0 * a0 + a1 * a1 + a2 * a2);
    }
    if (tid >= 64 && tid < 67) {
        int c = tid - 64;
        float s = 0.f;
        for (int k = 0; k < K_; k++) s += sV[k][c];
        sGsum[c] = s;
    }
    __syncthreads();

    if (tid == 0) {
        float m0 = sGsum[0] * (1.f / K_), m1 = sGsum[1] * (1.f / K_), m2 = sGsum[2] * (1.f / K_);
        float mm = fmaxf(m0, fmaxf(m1, m2));
        float e0 = __expf(m0 - mm), e1 = __expf(m1 - mm), e2 = __expf(m2 - mm);
        float inv = 1.f / (e0 + e1 + e2);
        float g0 = sF[64], g1 = sF[65], g2 = sF[66];
        float gm = fmaxf(g0, fmaxf(g1, g2));
        float f0 = __expf(g0 - gm), f1 = __expf(g1 - gm), f2 = __expf(g2 - gm);
        float inv2 = 1.f / (f0 + f1 + f2);
        sGD[0] = fabsf(e0 * inv - f0 * inv2);
        sGD[1] = fabsf(e1 * inv - f1 * inv2);
        sGD[2] = fabsf(e2 * inv - f2 * inv2);
    }
    __syncthreads();

    {
        int k = tid >> 3, l = tid & 7;
        float s = 0.f;
        for (int c = l; c < 67; c += 8) {
            float v = (c < D_) ? (sF[c] - sV[k][4 + c]) : (sF[c] - sGD[c - D_]);
            s += v * v;
        }
        s += __shfl_xor(s, 1); s += __shfl_xor(s, 2); s += __shfl_xor(s, 4);
        if (l == 0) sV[k][68] = sqrtf(s);
    }
    __syncthreads();

    if (tid < NC_) {
        const float* Pc = P + tid;
        float base = 0.f;
#pragma unroll 4
        for (int i = 0; i < 64; i++) base += Pc[(size_t)i * NC_] * sF[i];
#pragma unroll
        for (int j = 0; j < 3; j++) {
            base += Pc[(size_t)(64 + j) * NC_] * sF[64 + j]
                  + Pc[(size_t)(67 + j) * NC_] * sGD[j];
        }

        float acc[K_];
#pragma unroll
        for (int k = 0; k < K_; k++) acc[k] = 0.f;

        {
            float q0 = Pc[(size_t)70 * NC_];
            float q1 = Pc[(size_t)71 * NC_];
            float q2 = Pc[(size_t)72 * NC_];
            float q3 = Pc[(size_t)73 * NC_];
#pragma unroll
            for (int k = 0; k < K_; k++) {
                float4 v = *(const float4*)&sV[k][0];
                acc[k] = fmaf(v.x, q0, fmaf(v.y, q1, fmaf(v.z, q2, fmaf(v.w, q3, acc[k]))));
            }
        }
        for (int gi = 0; gi < 16; gi++) {
            int i0 = gi * 4;
            float q0 = Pc[(size_t)(74 + i0 + 0) * NC_];
            float q1 = Pc[(size_t)(74 + i0 + 1) * NC_];
            float q2 = Pc[(size_t)(74 + i0 + 2) * NC_];
            float q3 = Pc[(size_t)(74 + i0 + 3) * NC_];
#pragma unroll
            for (int k = 0; k < K_; k++) {
                float4 v = *(const float4*)&sV[k][4 + i0];
                acc[k] = fmaf(v.x, q0, fmaf(v.y, q1, fmaf(v.z, q2, fmaf(v.w, q3, acc[k]))));
            }
        }
        {
            float q0 = Pc[(size_t)138 * NC_];
#pragma unroll
            for (int k = 0; k < K_; k++) acc[k] = fmaf(sV[k][68], q0, acc[k]);
        }

        float m = -1e30f;
#pragma unroll
        for (int k = 0; k < K_; k++) {
            float v = base + acc[k];
            v = (v > 0.f) ? v : 0.2f * v;   // leaky_relu(., 0.2)
            acc[k] = v;
            m = fmaxf(m, v);
        }
        float ssum = 0.f;
#pragma unroll
        for (int k = 0; k < K_; k++) { float e = __expf(acc[k] - m); acc[k] = e; ssum += e; }
        float inv = 1.f / ssum;

        int col; float addv; float sgn;
        if      (tid < 3)   { col = tid;       addv = 0.f;           sgn = 1.f; }
        else if (tid < 6)   { col = 0;         addv = sF[61 + tid];  sgn = 0.f; }
        else if (tid < 9)   { col = tid - 6;   addv = sF[58 + tid];  sgn = -1.f; }
        else if (tid == 9)  { col = 3;         addv = 0.f;           sgn = 1.f; }
        else if (tid < 74)  { col = tid - 6;   addv = 0.f;           sgn = 1.f; }
        else if (tid < 77)  { col = 0;         addv = sGD[tid - 74]; sgn = 0.f; }
        else if (tid < 144) { col = 0;         addv = sF[tid - 77];  sgn = 0.f; }
        else if (tid < 208) { col = tid - 140; addv = sF[tid - 144]; sgn = -1.f; }
        else if (tid < 211) { col = 0;         addv = sF[tid - 144] - sGD[tid - 208]; sgn = 0.f; }
        else                { col = 68;        addv = 0.f;           sgn = 1.f; }
        float s = 0.f;
#pragma unroll
        for (int k = 0; k < K_; k++) s += acc[k] * sV[k][col];
        sPool[tid] = addv + sgn * (s * inv);
    }
    __syncthreads();

    if (tid < CO_) {
        const float* w = W1 + (size_t)tid * NC_;
        float accO = 0.f;
        for (int c = 0; c < NC_; c += 4) {
            float4 wv = *(const float4*)(w + c);
            accO += wv.x * sPool[c] + wv.y * sPool[c + 1] + wv.z * sPool[c + 2] + wv.w * sPool[c + 3];
        }
        accO += B1[tid];
        out1[((size_t)b * CO_ + tid) * NP_ + n] = accO;
    }
}

// ---------------------------------------------------------------------------
extern "C" void kernel_launch(void* const* d_in, const int* in_sizes, int n_in,
                              void* d_out, int out_size, void* d_ws, size_t ws_size,
                              hipStream_t stream) {
    (void)in_sizes; (void)n_in; (void)out_size; (void)ws_size;
    const float* xyz      = (const float*)d_in[0];
    const float* features = (const float*)d_in[1];
    const float* A        = (const float*)d_in[2];
    const float* W1       = (const float*)d_in[3];
    const float* B1       = (const float*)d_in[4];
    float* out0 = (float*)d_out;                     // new_xyz (B,1024,3) f32
    float* out1 = out0 + (size_t)B_ * NP_ * 3;       // features (B,128,1024) f32

    // workspace: fpsIdx(32KB) | P(118KB) | featT(8MB)  (~8.2 MB)
    char*  wsB    = (char*)d_ws;
    int*   fpsIdx = (int*)wsB;
    float* P      = (float*)(wsB + 32768);
    float* featT  = (float*)(wsB + 32768 + 118016);

    fold_kernel<<<dim3((PROWS * NC_ + 255) / 256), dim3(256), 0, stream>>>(A, P);
    transpose_kernel<<<dim3(N_ / 32, D_ / 32, B_), dim3(32, 8), 0, stream>>>(features, featT);
    fps_kernel<<<dim3(B_), dim3(FPS_T), 0, stream>>>(xyz, fpsIdx, out0);
    fused_kernel<<<dim3(B_ * NP_), dim3(256), 0, stream>>>(featT, xyz, out0, fpsIdx,
                                                           P, W1, B1, out1);
}

// Round 19
// 1217.571 us; speedup vs baseline: 1.3957x; 1.3957x over previous
//
#include <hip/hip_runtime.h>
#include <hip/hip_bf16.h>

#define B_    8
#define N_    4096
#define D_    64
#define NP_   1024
#define K_    32
#define NC_   212
#define CO_   128
#define FPS_T 256
#define SVW   72
#define PROWS 139

__device__ __forceinline__ float f32add(float a, float b) { return __fadd_rn(a, b); }
__device__ __forceinline__ float f32sub(float a, float b) { return __fsub_rn(a, b); }
__device__ __forceinline__ float f32mul(float a, float b) { return __fmul_rn(a, b); }

__device__ __forceinline__ void waveArgmaxDpp(float& best, int& bidx) {
#define AMAX_STEP(CTRL)                                                                     \
    {                                                                                       \
        int _v = __builtin_amdgcn_update_dpp(__float_as_int(best), __float_as_int(best),    \
                                             (CTRL), 0xf, 0xf, false);                      \
        int _i = __builtin_amdgcn_update_dpp(bidx, bidx, (CTRL), 0xf, 0xf, false);          \
        float _f = __int_as_float(_v);                                                      \
        if (_f > best || (_f == best && _i < bidx)) { best = _f; bidx = _i; }               \
    }
    AMAX_STEP(0x111);  // row_shr:1
    AMAX_STEP(0x112);  // row_shr:2
    AMAX_STEP(0x114);  // row_shr:4
    AMAX_STEP(0x118);  // row_shr:8
    AMAX_STEP(0x142);  // row_bcast:15
    AMAX_STEP(0x143);  // row_bcast:31
#undef AMAX_STEP
    best = __int_as_float(__builtin_amdgcn_readlane(__float_as_int(best), 63));
    bidx = __builtin_amdgcn_readlane(bidx, 63);
}

// ---------------------------------------------------------------------------
// Kernel A: fold A into P[139][212] (one-time, proven r16).
// ---------------------------------------------------------------------------
__global__ void fold_kernel(const float* __restrict__ A, float* __restrict__ P) {
    int x = blockIdx.x * 256 + threadIdx.x;
    if (x >= PROWS * NC_) return;
    int r = x / NC_, c = x % NC_;
    float v;
    if      (r < 64)  v = A[(size_t)(77 + r) * NC_ + c] + A[(size_t)(144 + r) * NC_ + c];
    else if (r < 67)  { int j = r - 64;
                        v = (A[(size_t)(3 + j) * NC_ + c] + A[(size_t)(141 + j) * NC_ + c])
                          + A[(size_t)(208 + j) * NC_ + c]; }
    else if (r < 70)  { int j = r - 67;
                        v = A[(size_t)(74 + j) * NC_ + c] - A[(size_t)(208 + j) * NC_ + c]; }
    else if (r < 73)  { int j = r - 70;
                        v = A[(size_t)j * NC_ + c] - A[(size_t)(6 + j) * NC_ + c]; }
    else if (r == 73) v = A[(size_t)9 * NC_ + c];
    else if (r < 138) { int i = r - 74;
                        v = A[(size_t)(10 + i) * NC_ + c] - A[(size_t)(144 + i) * NC_ + c]; }
    else              v = A[(size_t)211 * NC_ + c];
    P[(size_t)r * NC_ + c] = v;
}

// ---------------------------------------------------------------------------
// Kernel B: transpose features (B,64,N) -> featT (B,N,64) (proven r16).
// ---------------------------------------------------------------------------
__global__ void transpose_kernel(const float* __restrict__ in, float* __restrict__ out) {
    __shared__ float tile[32][33];
    int b  = blockIdx.z;
    int n0 = blockIdx.x * 32, d0 = blockIdx.y * 32;
    const float* src = in  + (size_t)b * D_ * N_;
    float*       dst = out + (size_t)b * N_ * D_;
    int tx = threadIdx.x, ty = threadIdx.y;
#pragma unroll
    for (int r = 0; r < 32; r += 8)
        tile[r + ty][tx] = src[(size_t)(d0 + r + ty) * N_ + n0 + tx];
    __syncthreads();
#pragma unroll
    for (int r = 0; r < 32; r += 8)
        dst[(size_t)(n0 + r + ty) * D_ + d0 + tx] = tile[tx][r + ty];
}

// ---------------------------------------------------------------------------
// Kernel 1: FPS — EXACTLY the r8-proven kernel (955 us; fused dist-update +
// select, DPP argmax, parity-buffered merge; bit-exact vs numpy-f32).
// r18's tree-select regressed 47% — this formulation is the local optimum.
// ---------------------------------------------------------------------------
__global__ __launch_bounds__(FPS_T) void fps_kernel(
    const float* __restrict__ xyz,
    int* __restrict__ fpsIdx, float* __restrict__ out0) {
    int b = blockIdx.x;
    const float* P = xyz + (size_t)b * N_ * 3;
    __shared__ float X[N_], Y[N_], Z[N_];
    __shared__ int   hist[NP_];
    __shared__ float redV[2][FPS_T / 64];
    __shared__ int   redI[2][FPS_T / 64];
    int tid = threadIdx.x;
    for (int i = tid; i < N_; i += FPS_T) {
        X[i] = P[i * 3 + 0];
        Y[i] = P[i * 3 + 1];
        Z[i] = P[i * 3 + 2];
    }
    if (tid == 0) hist[0] = 0;
    __syncthreads();

    const int PPT = N_ / FPS_T;  // 16
    float px[PPT], py[PPT], pz[PPT], dist[PPT];
#pragma unroll
    for (int c = 0; c < PPT; c++) {
        int j = tid + FPS_T * c;
        px[c] = X[j]; py[c] = Y[j]; pz[c] = Z[j];
        dist[c] = 1e10f;
    }
    int last = 0;
    for (int it = 1; it < NP_; ++it) {
        float lx = X[last], ly = Y[last], lz = Z[last];
        float best = -1.0f; int bidx = 0;
#pragma unroll
        for (int c = 0; c < PPT; c++) {
            float dx = f32sub(px[c], lx), dy = f32sub(py[c], ly), dz = f32sub(pz[c], lz);
            float nd = f32add(f32add(f32mul(dx, dx), f32mul(dy, dy)), f32mul(dz, dz));
            float d  = fminf(dist[c], nd);
            dist[c] = d;
            if (d > best) { best = d; bidx = tid + FPS_T * c; }   // ties: lowest j
        }
        waveArgmaxDpp(best, bidx);
        int par = it & 1;
        if ((tid & 63) == 0) { redV[par][tid >> 6] = best; redI[par][tid >> 6] = bidx; }
        __syncthreads();  // single barrier per iter; parity double-buffer makes it safe
        float bv = redV[par][0]; int bi = redI[par][0];
#pragma unroll
        for (int w = 1; w < FPS_T / 64; w++) {
            float ov = redV[par][w]; int oi = redI[par][w];
            if (ov > bv || (ov == bv && oi < bi)) { bv = ov; bi = oi; }
        }
        last = bi;
        if (tid == 0) hist[it] = last;
    }
    __syncthreads();
    for (int i = tid; i < NP_; i += FPS_T) {
        int j = hist[i];
        fpsIdx[b * NP_ + i] = j;
        size_t o = (size_t)(b * NP_ + i) * 3;
        out0[o + 0] = X[j]; out0[o + 1] = Y[j]; out0[o + 2] = Z[j];
    }
}

// ---------------------------------------------------------------------------
// Kernel 2: fused ball-query + feature_enhance + hetero_attention
// (EXACTLY the passing round-16 kernel: featT gathers + folded-P e-GEMM).
// ---------------------------------------------------------------------------
__global__ __launch_bounds__(256, 4) void fused_kernel(
    const float* __restrict__ featT, const float* __restrict__ xyz,
    const float* __restrict__ newxyz, const int* __restrict__ fpsIdx,
    const float* __restrict__ P, const float* __restrict__ W1,
    const float* __restrict__ B1, float* __restrict__ out1) {
    int q = blockIdx.x;
    int b = q >> 10, n = q & (NP_ - 1);
    int tid = threadIdx.x;
    __shared__ float sV[K_][SVW];
    __shared__ float sF[68];
    __shared__ float sFD[K_];
    __shared__ float sGD[3];
    __shared__ float sGsum[3];
    __shared__ float sPool[NC_];
    __shared__ int   sNb[K_];
    __shared__ int   sCnt;

    if (tid < D_) sF[tid] = featT[((size_t)b * N_ + fpsIdx[q]) * D_ + tid];
    if (tid >= D_ && tid < D_ + 3) sF[tid] = newxyz[q * 3 + (tid - D_)];

    if (tid < 64) {
        int lane = tid;
        if (lane < K_) sNb[lane] = N_ - 1;
        const float* Px = xyz + (size_t)b * N_ * 3;
        float qx = newxyz[q * 3 + 0];
        float qy = newxyz[q * 3 + 1];
        float qz = newxyz[q * 3 + 2];
        float sq = f32add(f32add(f32mul(qx, qx), f32mul(qy, qy)), f32mul(qz, qz));
        const float R2 = (float)(0.2 * 0.2);
        int count = 0;
        for (int base = 0; base < N_ && count < K_; base += 64) {
            int j = base + lane;
            float x = Px[j * 3 + 0];
            float y = Px[j * 3 + 1];
            float z = Px[j * 3 + 2];
            float sxj = f32add(f32add(f32mul(x, x), f32mul(y, y)), f32mul(z, z));
            float dot = __fmaf_rn(qz, z, __fmaf_rn(qy, y, __fmul_rn(qx, x)));
            float d2  = f32sub(f32add(sq, sxj), f32mul(2.0f, dot));
            bool in = (d2 <= R2);
            unsigned long long m = __ballot(in);
            if (in) {
                int pos = count + __popcll(m & ((1ull << lane) - 1ull));
                if (pos < K_) sNb[pos] = j;
            }
            count += __popcll(m);
        }
        if (lane == 0) sCnt = (count < K_) ? count : K_;
    }
    __syncthreads();
    int cnt = sCnt;

    {
        int k = tid >> 3, l = tid & 7;
        int j = (k < cnt || cnt == 0) ? sNb[k] : sNb[0];
        const float* src = featT + ((size_t)b * N_ + j) * D_;
        float4 v0 = *(const float4*)(src + l * 8);
        float4 v1 = *(const float4*)(src + l * 8 + 4);
        float* dst = &sV[k][4 + l * 8];
        dst[0] = v0.x; dst[1] = v0.y; dst[2] = v0.z; dst[3] = v0.w;
        dst[4] = v1.x; dst[5] = v1.y; dst[6] = v1.z; dst[7] = v1.w;
    }
    if (tid < 96) {
        int k = tid / 3, c = tid % 3;
        int j = (k < cnt || cnt == 0) ? sNb[k] : sNb[0];
        sV[k][c] = xyz[((size_t)b * N_ + j) * 3 + c];
        sV[k][69 + c] = 0.f;
    }
    __syncthreads();

    {
        int k = tid >> 3, ds = (tid & 7) * 8;
        float s = 0.f;
#pragma unroll
        for (int j = 0; j < 8; j++) s += fabsf(sF[ds + j] - sV[k][4 + ds + j]);
        s += __shfl_xor(s, 1); s += __shfl_xor(s, 2); s += __shfl_xor(s, 4);
        if ((tid & 7) == 0) sFD[k] = __expf(-s * (1.0f / 64.0f));
    }
    __syncthreads();

    if (tid < 96) {
        int k = tid / 3, c = tid % 3;
        sV[k][c] = sV[k][c] * sFD[k];
    }
    __syncthreads();

    if (tid < K_) {
        int k = tid;
        float a0 = sF[64] - sV[k][0], a1 = sF[65] - sV[k][1], a2 = sF[66] - sV[k][2];
        sV[k][3] = sqrtf(a0 * a0 + a1 * a1 + a2 * a2);
    }
    if (tid >= 64 && tid < 67) {
        int c = tid - 64;
        float s = 0.f;
        for (int k = 0; k < K_; k++) s += sV[k][c];
        sGsum[c] = s;
    }
    __syncthreads();

    if (tid == 0) {
        float m0 = sGsum[0] * (1.f / K_), m1 = sGsum[1] * (1.f / K_), m2 = sGsum[2] * (1.f / K_);
        float mm = fmaxf(m0, fmaxf(m1, m2));
        float e0 = __expf(m0 - mm), e1 = __expf(m1 - mm), e2 = __expf(m2 - mm);
        float inv = 1.f / (e0 + e1 + e2);
        float g0 = sF[64], g1 = sF[65], g2 = sF[66];
        float gm = fmaxf(g0, fmaxf(g1, g2));
        float f0 = __expf(g0 - gm), f1 = __expf(g1 - gm), f2 = __expf(g2 - gm);
        float inv2 = 1.f / (f0 + f1 + f2);
        sGD[0] = fabsf(e0 * inv - f0 * inv2);
        sGD[1] = fabsf(e1 * inv - f1 * inv2);
        sGD[2] = fabsf(e2 * inv - f2 * inv2);
    }
    __syncthreads();

    {
        int k = tid >> 3, l = tid & 7;
        float s = 0.f;
        for (int c = l; c < 67; c += 8) {
            float v = (c < D_) ? (sF[c] - sV[k][4 + c]) : (sF[c] - sGD[c - D_]);
            s += v * v;
        }
        s += __shfl_xor(s, 1); s += __shfl_xor(s, 2); s += __shfl_xor(s, 4);
        if (l == 0) sV[k][68] = sqrtf(s);
    }
    __syncthreads();

    if (tid < NC_) {
        const float* Pc = P + tid;
        float base = 0.f;
#pragma unroll 4
        for (int i = 0; i < 64; i++) base += Pc[(size_t)i * NC_] * sF[i];
#pragma unroll
        for (int j = 0; j < 3; j++) {
            base += Pc[(size_t)(64 + j) * NC_] * sF[64 + j]
                  + Pc[(size_t)(67 + j) * NC_] * sGD[j];
        }

        float acc[K_];
#pragma unroll
        for (int k = 0; k < K_; k++) acc[k] = 0.f;

        {
            float q0 = Pc[(size_t)70 * NC_];
            float q1 = Pc[(size_t)71 * NC_];
            float q2 = Pc[(size_t)72 * NC_];
            float q3 = Pc[(size_t)73 * NC_];
#pragma unroll
            for (int k = 0; k < K_; k++) {
                float4 v = *(const float4*)&sV[k][0];
                acc[k] = fmaf(v.x, q0, fmaf(v.y, q1, fmaf(v.z, q2, fmaf(v.w, q3, acc[k]))));
            }
        }
        for (int gi = 0; gi < 16; gi++) {
            int i0 = gi * 4;
            float q0 = Pc[(size_t)(74 + i0 + 0) * NC_];
            float q1 = Pc[(size_t)(74 + i0 + 1) * NC_];
            float q2 = Pc[(size_t)(74 + i0 + 2) * NC_];
            float q3 = Pc[(size_t)(74 + i0 + 3) * NC_];
#pragma unroll
            for (int k = 0; k < K_; k++) {
                float4 v = *(const float4*)&sV[k][4 + i0];
                acc[k] = fmaf(v.x, q0, fmaf(v.y, q1, fmaf(v.z, q2, fmaf(v.w, q3, acc[k]))));
            }
        }
        {
            float q0 = Pc[(size_t)138 * NC_];
#pragma unroll
            for (int k = 0; k < K_; k++) acc[k] = fmaf(sV[k][68], q0, acc[k]);
        }

        float m = -1e30f;
#pragma unroll
        for (int k = 0; k < K_; k++) {
            float v = base + acc[k];
            v = (v > 0.f) ? v : 0.2f * v;   // leaky_relu(., 0.2)
            acc[k] = v;
            m = fmaxf(m, v);
        }
        float ssum = 0.f;
#pragma unroll
        for (int k = 0; k < K_; k++) { float e = __expf(acc[k] - m); acc[k] = e; ssum += e; }
        float inv = 1.f / ssum;

        int col; float addv; float sgn;
        if      (tid < 3)   { col = tid;       addv = 0.f;           sgn = 1.f; }
        else if (tid < 6)   { col = 0;         addv = sF[61 + tid];  sgn = 0.f; }
        else if (tid < 9)   { col = tid - 6;   addv = sF[58 + tid];  sgn = -1.f; }
        else if (tid == 9)  { col = 3;         addv = 0.f;           sgn = 1.f; }
        else if (tid < 74)  { col = tid - 6;   addv = 0.f;           sgn = 1.f; }
        else if (tid < 77)  { col = 0;         addv = sGD[tid - 74]; sgn = 0.f; }
        else if (tid < 144) { col = 0;         addv = sF[tid - 77];  sgn = 0.f; }
        else if (tid < 208) { col = tid - 140; addv = sF[tid - 144]; sgn = -1.f; }
        else if (tid < 211) { col = 0;         addv = sF[tid - 144] - sGD[tid - 208]; sgn = 0.f; }
        else                { col = 68;        addv = 0.f;           sgn = 1.f; }
        float s = 0.f;
#pragma unroll
        for (int k = 0; k < K_; k++) s += acc[k] * sV[k][col];
        sPool[tid] = addv + sgn * (s * inv);
    }
    __syncthreads();

    if (tid < CO_) {
        const float* w = W1 + (size_t)tid * NC_;
        float accO = 0.f;
        for (int c = 0; c < NC_; c += 4) {
            float4 wv = *(const float4*)(w + c);
            accO += wv.x * sPool[c] + wv.y * sPool[c + 1] + wv.z * sPool[c + 2] + wv.w * sPool[c + 3];
        }
        accO += B1[tid];
        out1[((size_t)b * CO_ + tid) * NP_ + n] = accO;
    }
}

// ---------------------------------------------------------------------------
extern "C" void kernel_launch(void* const* d_in, const int* in_sizes, int n_in,
                              void* d_out, int out_size, void* d_ws, size_t ws_size,
                              hipStream_t stream) {
    (void)in_sizes; (void)n_in; (void)out_size; (void)ws_size;
    const float* xyz      = (const float*)d_in[0];
    const float* features = (const float*)d_in[1];
    const float* A        = (const float*)d_in[2];
    const float* W1       = (const float*)d_in[3];
    const float* B1       = (const float*)d_in[4];
    float* out0 = (float*)d_out;                     // new_xyz (B,1024,3) f32
    float* out1 = out0 + (size_t)B_ * NP_ * 3;       // features (B,128,1024) f32

    // workspace: fpsIdx(32KB) | P(118KB) | featT(8MB)  (~8.2 MB)
    char*  wsB    = (char*)d_ws;
    int*   fpsIdx = (int*)wsB;
    float* P      = (float*)(wsB + 32768);
    float* featT  = (float*)(wsB + 32768 + 118016);

    fold_kernel<<<dim3((PROWS * NC_ + 255) / 256), dim3(256), 0, stream>>>(A, P);
    transpose_kernel<<<dim3(N_ / 32, D_ / 32, B_), dim3(32, 8), 0, stream>>>(features, featT);
    fps_kernel<<<dim3(B_), dim3(FPS_T), 0, stream>>>(xyz, fpsIdx, out0);
    fused_kernel<<<dim3(B_ * NP_), dim3(256), 0, stream>>>(featT, xyz, out0, fpsIdx,
                                                           P, W1, B1, out1);
}

// Round 20
// 1210.411 us; speedup vs baseline: 1.4040x; 1.0059x over previous
//
#include <hip/hip_runtime.h>
#include <hip/hip_bf16.h>

#define B_    8
#define N_    4096
#define D_    64
#define NP_   1024
#define K_    32
#define NC_   212
#define CO_   128
#define FPS_T 256
#define SVW   72
#define PROWS 139
#define NTRB  2048   // transpose tile blocks: (N/32)*(D/32)*B = 128*2*8
#define NFLB  116    // fold blocks: ceil(139*212/256)

__device__ __forceinline__ float f32add(float a, float b) { return __fadd_rn(a, b); }
__device__ __forceinline__ float f32sub(float a, float b) { return __fsub_rn(a, b); }
__device__ __forceinline__ float f32mul(float a, float b) { return __fmul_rn(a, b); }

__device__ __forceinline__ void waveArgmaxDpp(float& best, int& bidx) {
#define AMAX_STEP(CTRL)                                                                     \
    {                                                                                       \
        int _v = __builtin_amdgcn_update_dpp(__float_as_int(best), __float_as_int(best),    \
                                             (CTRL), 0xf, 0xf, false);                      \
        int _i = __builtin_amdgcn_update_dpp(bidx, bidx, (CTRL), 0xf, 0xf, false);          \
        float _f = __int_as_float(_v);                                                      \
        if (_f > best || (_f == best && _i < bidx)) { best = _f; bidx = _i; }               \
    }
    AMAX_STEP(0x111);  // row_shr:1
    AMAX_STEP(0x112);  // row_shr:2
    AMAX_STEP(0x114);  // row_shr:4
    AMAX_STEP(0x118);  // row_shr:8
    AMAX_STEP(0x142);  // row_bcast:15
    AMAX_STEP(0x143);  // row_bcast:31
#undef AMAX_STEP
    best = __int_as_float(__builtin_amdgcn_readlane(__float_as_int(best), 63));
    bidx = __builtin_amdgcn_readlane(bidx, 63);
}

struct FpsSm {
    float X[N_], Y[N_], Z[N_];
    int   hist[NP_];
    float redV[2][FPS_T / 64];
    int   redI[2][FPS_T / 64];
};
struct TrSm { float tile[32][33]; };
union ComboSm { FpsSm f; TrSm t; };

// ---------------------------------------------------------------------------
// Kernel 1 (combo): blocks 0-7 = the r8-PROVEN FPS (byte-identical math,
// bit-exact vs numpy-f32). Blocks 8..2055 = one transpose tile each.
// Blocks 2056..2171 = fold A->P. NO inter-block communication of any kind —
// helpers are fire-and-forget; the fused kernel is stream-ordered after this
// dispatch. Hides the prologue (~25-45us) under FPS's serial shadow.
// ---------------------------------------------------------------------------
__global__ __launch_bounds__(FPS_T) void combo_kernel(
    const float* __restrict__ xyz, const float* __restrict__ features,
    const float* __restrict__ A,
    int* __restrict__ fpsIdx, float* __restrict__ out0,
    float* __restrict__ featT, float* __restrict__ Pm) {
    __shared__ ComboSm sm;
    int tid = threadIdx.x;

    if (blockIdx.x >= B_) {
        int t = blockIdx.x - B_;
        if (t < NTRB) {
            // ---- transpose tile: (B,64,N) -> featT (B,N,64) ----
            int n0 = (t & 127) * 32;           // N/32 = 128 tiles along n
            int d0 = ((t >> 7) & 1) * 32;      // D/32 = 2 tiles along d
            int b  = t >> 8;                   // 8 batches
            const float* src = features + (size_t)b * D_ * N_;
            float*       dst = featT    + (size_t)b * N_ * D_;
            int tx = tid & 31, ty = tid >> 5;  // (32,8)
#pragma unroll
            for (int r = 0; r < 32; r += 8)
                sm.t.tile[r + ty][tx] = src[(size_t)(d0 + r + ty) * N_ + n0 + tx];
            __syncthreads();
#pragma unroll
            for (int r = 0; r < 32; r += 8)
                dst[(size_t)(n0 + r + ty) * D_ + d0 + tx] = sm.t.tile[tx][r + ty];
        } else {
            // ---- fold A -> P[139][212] ----
            int x = (t - NTRB) * 256 + tid;
            if (x < PROWS * NC_) {
                int r = x / NC_, c = x % NC_;
                float v;
                if      (r < 64)  v = A[(size_t)(77 + r) * NC_ + c] + A[(size_t)(144 + r) * NC_ + c];
                else if (r < 67)  { int j = r - 64;
                                    v = (A[(size_t)(3 + j) * NC_ + c] + A[(size_t)(141 + j) * NC_ + c])
                                      + A[(size_t)(208 + j) * NC_ + c]; }
                else if (r < 70)  { int j = r - 67;
                                    v = A[(size_t)(74 + j) * NC_ + c] - A[(size_t)(208 + j) * NC_ + c]; }
                else if (r < 73)  { int j = r - 70;
                                    v = A[(size_t)j * NC_ + c] - A[(size_t)(6 + j) * NC_ + c]; }
                else if (r == 73) v = A[(size_t)9 * NC_ + c];
                else if (r < 138) { int i = r - 74;
                                    v = A[(size_t)(10 + i) * NC_ + c] - A[(size_t)(144 + i) * NC_ + c]; }
                else              v = A[(size_t)211 * NC_ + c];
                Pm[(size_t)r * NC_ + c] = v;
            }
        }
        return;
    }

    // ---- FPS role: byte-identical to the r8-proven kernel ----
    int b = blockIdx.x;
    const float* P = xyz + (size_t)b * N_ * 3;
    for (int i = tid; i < N_; i += FPS_T) {
        sm.f.X[i] = P[i * 3 + 0];
        sm.f.Y[i] = P[i * 3 + 1];
        sm.f.Z[i] = P[i * 3 + 2];
    }
    if (tid == 0) sm.f.hist[0] = 0;
    __syncthreads();

    const int PPT = N_ / FPS_T;  // 16
    float px[PPT], py[PPT], pz[PPT], dist[PPT];
#pragma unroll
    for (int c = 0; c < PPT; c++) {
        int j = tid + FPS_T * c;
        px[c] = sm.f.X[j]; py[c] = sm.f.Y[j]; pz[c] = sm.f.Z[j];
        dist[c] = 1e10f;
    }
    int last = 0;
    for (int it = 1; it < NP_; ++it) {
        float lx = sm.f.X[last], ly = sm.f.Y[last], lz = sm.f.Z[last];
        float best = -1.0f; int bidx = 0;
#pragma unroll
        for (int c = 0; c < PPT; c++) {
            float dx = f32sub(px[c], lx), dy = f32sub(py[c], ly), dz = f32sub(pz[c], lz);
            float nd = f32add(f32add(f32mul(dx, dx), f32mul(dy, dy)), f32mul(dz, dz));
            float d  = fminf(dist[c], nd);
            dist[c] = d;
            if (d > best) { best = d; bidx = tid + FPS_T * c; }   // ties: lowest j
        }
        waveArgmaxDpp(best, bidx);
        int par = it & 1;
        if ((tid & 63) == 0) { sm.f.redV[par][tid >> 6] = best; sm.f.redI[par][tid >> 6] = bidx; }
        __syncthreads();  // single barrier per iter; parity double-buffer makes it safe
        float bv = sm.f.redV[par][0]; int bi = sm.f.redI[par][0];
#pragma unroll
        for (int w = 1; w < FPS_T / 64; w++) {
            float ov = sm.f.redV[par][w]; int oi = sm.f.redI[par][w];
            if (ov > bv || (ov == bv && oi < bi)) { bv = ov; bi = oi; }
        }
        last = bi;
        if (tid == 0) sm.f.hist[it] = last;
    }
    __syncthreads();
    for (int i = tid; i < NP_; i += FPS_T) {
        int j = sm.f.hist[i];
        fpsIdx[b * NP_ + i] = j;
        size_t o = (size_t)(b * NP_ + i) * 3;
        out0[o + 0] = sm.f.X[j]; out0[o + 1] = sm.f.Y[j]; out0[o + 2] = sm.f.Z[j];
    }
}

// ---------------------------------------------------------------------------
// Kernel 2: fused ball-query + feature_enhance + hetero_attention
// (EXACTLY the passing round-16/19 kernel: featT gathers + folded-P e-GEMM).
// ---------------------------------------------------------------------------
__global__ __launch_bounds__(256, 4) void fused_kernel(
    const float* __restrict__ featT, const float* __restrict__ xyz,
    const float* __restrict__ newxyz, const int* __restrict__ fpsIdx,
    const float* __restrict__ P, const float* __restrict__ W1,
    const float* __restrict__ B1, float* __restrict__ out1) {
    int q = blockIdx.x;
    int b = q >> 10, n = q & (NP_ - 1);
    int tid = threadIdx.x;
    __shared__ float sV[K_][SVW];
    __shared__ float sF[68];
    __shared__ float sFD[K_];
    __shared__ float sGD[3];
    __shared__ float sGsum[3];
    __shared__ float sPool[NC_];
    __shared__ int   sNb[K_];
    __shared__ int   sCnt;

    if (tid < D_) sF[tid] = featT[((size_t)b * N_ + fpsIdx[q]) * D_ + tid];
    if (tid >= D_ && tid < D_ + 3) sF[tid] = newxyz[q * 3 + (tid - D_)];

    if (tid < 64) {
        int lane = tid;
        if (lane < K_) sNb[lane] = N_ - 1;
        const float* Px = xyz + (size_t)b * N_ * 3;
        float qx = newxyz[q * 3 + 0];
        float qy = newxyz[q * 3 + 1];
        float qz = newxyz[q * 3 + 2];
        float sq = f32add(f32add(f32mul(qx, qx), f32mul(qy, qy)), f32mul(qz, qz));
        const float R2 = (float)(0.2 * 0.2);
        int count = 0;
        for (int base = 0; base < N_ && count < K_; base += 64) {
            int j = base + lane;
            float x = Px[j * 3 + 0];
            float y = Px[j * 3 + 1];
            float z = Px[j * 3 + 2];
            float sxj = f32add(f32add(f32mul(x, x), f32mul(y, y)), f32mul(z, z));
            float dot = __fmaf_rn(qz, z, __fmaf_rn(qy, y, __fmul_rn(qx, x)));
            float d2  = f32sub(f32add(sq, sxj), f32mul(2.0f, dot));
            bool in = (d2 <= R2);
            unsigned long long m = __ballot(in);
            if (in) {
                int pos = count + __popcll(m & ((1ull << lane) - 1ull));
                if (pos < K_) sNb[pos] = j;
            }
            count += __popcll(m);
        }
        if (lane == 0) sCnt = (count < K_) ? count : K_;
    }
    __syncthreads();
    int cnt = sCnt;

    {
        int k = tid >> 3, l = tid & 7;
        int j = (k < cnt || cnt == 0) ? sNb[k] : sNb[0];
        const float* src = featT + ((size_t)b * N_ + j) * D_;
        float4 v0 = *(const float4*)(src + l * 8);
        float4 v1 = *(const float4*)(src + l * 8 + 4);
        float* dst = &sV[k][4 + l * 8];
        dst[0] = v0.x; dst[1] = v0.y; dst[2] = v0.z; dst[3] = v0.w;
        dst[4] = v1.x; dst[5] = v1.y; dst[6] = v1.z; dst[7] = v1.w;
    }
    if (tid < 96) {
        int k = tid / 3, c = tid % 3;
        int j = (k < cnt || cnt == 0) ? sNb[k] : sNb[0];
        sV[k][c] = xyz[((size_t)b * N_ + j) * 3 + c];
        sV[k][69 + c] = 0.f;
    }
    __syncthreads();

    {
        int k = tid >> 3, ds = (tid & 7) * 8;
        float s = 0.f;
#pragma unroll
        for (int j = 0; j < 8; j++) s += fabsf(sF[ds + j] - sV[k][4 + ds + j]);
        s += __shfl_xor(s, 1); s += __shfl_xor(s, 2); s += __shfl_xor(s, 4);
        if ((tid & 7) == 0) sFD[k] = __expf(-s * (1.0f / 64.0f));
    }
    __syncthreads();

    if (tid < 96) {
        int k = tid / 3, c = tid % 3;
        sV[k][c] = sV[k][c] * sFD[k];
    }
    __syncthreads();

    if (tid < K_) {
        int k = tid;
        float a0 = sF[64] - sV[k][0], a1 = sF[65] - sV[k][1], a2 = sF[66] - sV[k][2];
        sV[k][3] = sqrtf(a0 * a0 + a1 * a1 + a2 * a2);
    }
    if (tid >= 64 && tid < 67) {
        int c = tid - 64;
        float s = 0.f;
        for (int k = 0; k < K_; k++) s += sV[k][c];
        sGsum[c] = s;
    }
    __syncthreads();

    if (tid == 0) {
        float m0 = sGsum[0] * (1.f / K_), m1 = sGsum[1] * (1.f / K_), m2 = sGsum[2] * (1.f / K_);
        float mm = fmaxf(m0, fmaxf(m1, m2));
        float e0 = __expf(m0 - mm), e1 = __expf(m1 - mm), e2 = __expf(m2 - mm);
        float inv = 1.f / (e0 + e1 + e2);
        float g0 = sF[64], g1 = sF[65], g2 = sF[66];
        float gm = fmaxf(g0, fmaxf(g1, g2));
        float f0 = __expf(g0 - gm), f1 = __expf(g1 - gm), f2 = __expf(g2 - gm);
        float inv2 = 1.f / (f0 + f1 + f2);
        sGD[0] = fabsf(e0 * inv - f0 * inv2);
        sGD[1] = fabsf(e1 * inv - f1 * inv2);
        sGD[2] = fabsf(e2 * inv - f2 * inv2);
    }
    __syncthreads();

    {
        int k = tid >> 3, l = tid & 7;
        float s = 0.f;
        for (int c = l; c < 67; c += 8) {
            float v = (c < D_) ? (sF[c] - sV[k][4 + c]) : (sF[c] - sGD[c - D_]);
            s += v * v;
        }
        s += __shfl_xor(s, 1); s += __shfl_xor(s, 2); s += __shfl_xor(s, 4);
        if (l == 0) sV[k][68] = sqrtf(s);
    }
    __syncthreads();

    if (tid < NC_) {
        const float* Pc = P + tid;
        float base = 0.f;
#pragma unroll 4
        for (int i = 0; i < 64; i++) base += Pc[(size_t)i * NC_] * sF[i];
#pragma unroll
        for (int j = 0; j < 3; j++) {
            base += Pc[(size_t)(64 + j) * NC_] * sF[64 + j]
                  + Pc[(size_t)(67 + j) * NC_] * sGD[j];
        }

        float acc[K_];
#pragma unroll
        for (int k = 0; k < K_; k++) acc[k] = 0.f;

        {
            float q0 = Pc[(size_t)70 * NC_];
            float q1 = Pc[(size_t)71 * NC_];
            float q2 = Pc[(size_t)72 * NC_];
            float q3 = Pc[(size_t)73 * NC_];
#pragma unroll
            for (int k = 0; k < K_; k++) {
                float4 v = *(const float4*)&sV[k][0];
                acc[k] = fmaf(v.x, q0, fmaf(v.y, q1, fmaf(v.z, q2, fmaf(v.w, q3, acc[k]))));
            }
        }
        for (int gi = 0; gi < 16; gi++) {
            int i0 = gi * 4;
            float q0 = Pc[(size_t)(74 + i0 + 0) * NC_];
            float q1 = Pc[(size_t)(74 + i0 + 1) * NC_];
            float q2 = Pc[(size_t)(74 + i0 + 2) * NC_];
            float q3 = Pc[(size_t)(74 + i0 + 3) * NC_];
#pragma unroll
            for (int k = 0; k < K_; k++) {
                float4 v = *(const float4*)&sV[k][4 + i0];
                acc[k] = fmaf(v.x, q0, fmaf(v.y, q1, fmaf(v.z, q2, fmaf(v.w, q3, acc[k]))));
            }
        }
        {
            float q0 = Pc[(size_t)138 * NC_];
#pragma unroll
            for (int k = 0; k < K_; k++) acc[k] = fmaf(sV[k][68], q0, acc[k]);
        }

        float m = -1e30f;
#pragma unroll
        for (int k = 0; k < K_; k++) {
            float v = base + acc[k];
            v = (v > 0.f) ? v : 0.2f * v;   // leaky_relu(., 0.2)
            acc[k] = v;
            m = fmaxf(m, v);
        }
        float ssum = 0.f;
#pragma unroll
        for (int k = 0; k < K_; k++) { float e = __expf(acc[k] - m); acc[k] = e; ssum += e; }
        float inv = 1.f / ssum;

        int col; float addv; float sgn;
        if      (tid < 3)   { col = tid;       addv = 0.f;           sgn = 1.f; }
        else if (tid < 6)   { col = 0;         addv = sF[61 + tid];  sgn = 0.f; }
        else if (tid < 9)   { col = tid - 6;   addv = sF[58 + tid];  sgn = -1.f; }
        else if (tid == 9)  { col = 3;         addv = 0.f;           sgn = 1.f; }
        else if (tid < 74)  { col = tid - 6;   addv = 0.f;           sgn = 1.f; }
        else if (tid < 77)  { col = 0;         addv = sGD[tid - 74]; sgn = 0.f; }
        else if (tid < 144) { col = 0;         addv = sF[tid - 77];  sgn = 0.f; }
        else if (tid < 208) { col = tid - 140; addv = sF[tid - 144]; sgn = -1.f; }
        else if (tid < 211) { col = 0;         addv = sF[tid - 144] - sGD[tid - 208]; sgn = 0.f; }
        else                { col = 68;        addv = 0.f;           sgn = 1.f; }
        float s = 0.f;
#pragma unroll
        for (int k = 0; k < K_; k++) s += acc[k] * sV[k][col];
        sPool[tid] = addv + sgn * (s * inv);
    }
    __syncthreads();

    if (tid < CO_) {
        const float* w = W1 + (size_t)tid * NC_;
        float accO = 0.f;
        for (int c = 0; c < NC_; c += 4) {
            float4 wv = *(const float4*)(w + c);
            accO += wv.x * sPool[c] + wv.y * sPool[c + 1] + wv.z * sPool[c + 2] + wv.w * sPool[c + 3];
        }
        accO += B1[tid];
        out1[((size_t)b * CO_ + tid) * NP_ + n] = accO;
    }
}

// ---------------------------------------------------------------------------
extern "C" void kernel_launch(void* const* d_in, const int* in_sizes, int n_in,
                              void* d_out, int out_size, void* d_ws, size_t ws_size,
                              hipStream_t stream) {
    (void)in_sizes; (void)n_in; (void)out_size; (void)ws_size;
    const float* xyz      = (const float*)d_in[0];
    const float* features = (const float*)d_in[1];
    const float* A        = (const float*)d_in[2];
    const float* W1       = (const float*)d_in[3];
    const float* B1       = (const float*)d_in[4];
    float* out0 = (float*)d_out;                     // new_xyz (B,1024,3) f32
    float* out1 = out0 + (size_t)B_ * NP_ * 3;       // features (B,128,1024) f32

    // workspace: fpsIdx(32KB) | P(118KB) | featT(8MB)  (~8.2 MB)
    char*  wsB    = (char*)d_ws;
    int*   fpsIdx = (int*)wsB;
    float* P      = (float*)(wsB + 32768);
    float* featT  = (float*)(wsB + 32768 + 118016);

    combo_kernel<<<dim3(B_ + NTRB + NFLB), dim3(FPS_T), 0, stream>>>(
        xyz, features, A, fpsIdx, out0, featT, P);
    fused_kernel<<<dim3(B_ * NP_), dim3(256), 0, stream>>>(featT, xyz, out0, fpsIdx,
                                                           P, W1, B1, out1);
}